// Round 2
// baseline (616.594 us; speedup 1.0000x reference)
//
#include <hip/hip_runtime.h>

// Problem constants
constexpr int B  = 64, S = 512, H = 768, WE = 4, ML = 5, D = 50, T = 21;
constexpr int NT = B * S;          // 32768 tokens
constexpr int HF = H + WE * D;     // 968 feature dim
constexpr int HP = 1024;           // padded feature dim (for clean float4 tiling)
constexpr int TPW = 4;             // tokens per wave in the logits kernel
constexpr float LOG2E = 1.4426950408889634f;
constexpr float LN2   = 0.6931471805599453f;

// ---------------------------------------------------------------------------
// Kernel 0: transpose + zero-pad W (968x21) -> Wp (21x1024) so the matvec can
// read W columns as aligned, coalesced float4.
// ---------------------------------------------------------------------------
__global__ void k_wprep(const float* __restrict__ W, float* __restrict__ Wp) {
  int idx = blockIdx.x * 256 + threadIdx.x;
  if (idx < T * HP) {
    int t = idx >> 10;          // /1024
    int h = idx & (HP - 1);     // %1024
    Wp[idx] = (h < HF) ? W[h * T + t] : 0.f;
  }
}

// ---------------------------------------------------------------------------
// Kernel 1: fused lexicon gather + weighted sum + concat + matvec + bias.
// One wave handles TPW=4 tokens. Each lane owns 4 consecutive h values per
// iteration (4 iters cover h=0..1023); 84 fp32 accumulators per lane; butterfly
// shuffle reduce; lane 0 stores 21 logits per token (+bias).
// ---------------------------------------------------------------------------
__launch_bounds__(256)
__global__ void k_logits(const float* __restrict__ seq,
                         const int*   __restrict__ ids,
                         const float* __restrict__ wts,
                         const float* __restrict__ emb,
                         const float* __restrict__ Wp,
                         const float* __restrict__ bias,
                         float* __restrict__ out) {
  __shared__ __align__(16) float lexs[4][TPW * 200];   // per-wave lex features
  const int wave = threadIdx.x >> 6;
  const int lane = threadIdx.x & 63;
  const int tok0 = (blockIdx.x * 4 + wave) * TPW;

  // ---- lexicon: lex[k][w*50+d] = sum_l wts[tok,w,l] * emb[ids[tok,w,l], d]
  for (int o = lane; o < TPW * 200; o += 64) {
    int k = o / 200, r = o - k * 200;
    int w = r / 50,  d = r - w * 50;
    int base = ((tok0 + k) * WE + w) * ML;
    float a = 0.f;
#pragma unroll
    for (int l = 0; l < ML; ++l) {
      int   id = ids[base + l];
      float wt = wts[base + l];
      a += wt * emb[(long)id * D + d];
    }
    lexs[wave][o] = a;
  }
  __syncthreads();

  // ---- matvec: logits[tok][t] = sum_h feat[tok][h] * Wp[t][h]
  float acc[TPW][T];
#pragma unroll
  for (int k = 0; k < TPW; ++k)
#pragma unroll
    for (int t = 0; t < T; ++t) acc[k][t] = 0.f;

#pragma unroll
  for (int it = 0; it < 4; ++it) {
    const int h0 = it * 256 + lane * 4;
    float4 f[TPW];
#pragma unroll
    for (int k = 0; k < TPW; ++k) {
      if (h0 < H)        f[k] = *(const float4*)&seq[(long)(tok0 + k) * H + h0];
      else if (h0 < HF)  f[k] = *(const float4*)&lexs[wave][k * 200 + (h0 - H)];
      else               f[k] = make_float4(0.f, 0.f, 0.f, 0.f);
    }
#pragma unroll
    for (int t = 0; t < T; ++t) {
      float4 wv = *(const float4*)&Wp[t * HP + h0];
#pragma unroll
      for (int k = 0; k < TPW; ++k) {
        acc[k][t] += f[k].x * wv.x;
        acc[k][t] += f[k].y * wv.y;
        acc[k][t] += f[k].z * wv.z;
        acc[k][t] += f[k].w * wv.w;
      }
    }
  }

  // ---- cross-lane reduce (64 partials per output)
#pragma unroll
  for (int k = 0; k < TPW; ++k)
#pragma unroll
    for (int t = 0; t < T; ++t) {
      float v = acc[k][t];
#pragma unroll
      for (int m = 32; m; m >>= 1) v += __shfl_xor(v, m, 64);
      acc[k][t] = v;
    }

  if (lane == 0) {
#pragma unroll
    for (int k = 0; k < TPW; ++k)
#pragma unroll
      for (int t = 0; t < T; ++t)
        out[(long)(tok0 + k) * T + t] = acc[k][t] + bias[t];
  }
}

// ---------------------------------------------------------------------------
// Kernel 2: CRF negative log-likelihood pieces per batch element.
// One 64-thread block per sequence. lane j = lane%21 holds alpha[j]; the
// logsumexp over 21 source states is split across 3 lane groups (7 each).
// Writes part[b] = logZ_b - num_b.
// ---------------------------------------------------------------------------
__global__ void k_crf(const float* __restrict__ logits,
                      const int*   __restrict__ labels,
                      const int*   __restrict__ mask,
                      const float* __restrict__ start_t,
                      const float* __restrict__ end_t,
                      const float* __restrict__ trans,
                      float* __restrict__ part) {
  const int b = blockIdx.x;
  const int lane = threadIdx.x;       // block = 64 = 1 wave
  const long base = (long)b * S;
  const int j = lane % 21;
  int p = lane / 21; if (p == 3) p = 0;   // lane 63 duplicates lane 0's work
  const int i0 = p * 7;

  // preload this lane's 7 transition entries trans[i0+ii][j]
  float tr[7];
#pragma unroll
  for (int ii = 0; ii < 7; ++ii) tr[ii] = trans[(i0 + ii) * T + j];

  // ---- numerator (gold path score), parallel over s then butterfly reduce
  float np = 0.f; int cnt = 0;
  for (int s = lane; s < S; s += 64) {
    int tg = labels[base + s];
    int mk = mask[base + s];
    cnt += mk;
    if (s == 0) {
      np += start_t[tg] + logits[base * T + tg];
    } else {
      int tp = labels[base + s - 1];
      np += mk ? (trans[tp * T + tg] + logits[(base + s) * T + tg]) : 0.f;
    }
  }
#pragma unroll
  for (int m = 32; m; m >>= 1) {
    np  += __shfl_xor(np, m, 64);
    cnt += __shfl_xor(cnt, m, 64);
  }
  int last = cnt - 1;
  int lt = labels[base + last];
  float num = np + end_t[lt];

  // ---- forward algorithm (logZ), sequential over s, alpha in registers
  float a = start_t[j] + logits[base * T + j];
  float e_nxt = logits[(base + 1) * T + j];
  int   m_nxt = mask[base + 1];
  for (int s = 1; s < S; ++s) {
    float e = e_nxt; int mk = m_nxt;
    if (s + 1 < S) {
      e_nxt = logits[(base + s + 1) * T + j];
      m_nxt = mask[base + s + 1];
    }
    float x[7]; float xm = -3e38f;
#pragma unroll
    for (int ii = 0; ii < 7; ++ii) {
      float ai = __shfl(a, i0 + ii, 64);
      x[ii] = ai + tr[ii];
      xm = fmaxf(xm, x[ii]);
    }
    // combine the 3 partial maxima for column j
    float m1 = __shfl(xm, j, 64);
    float m2 = __shfl(xm, j + 21, 64);
    float m3 = __shfl(xm, j + 42, 64);
    float mm = fmaxf(fmaxf(m1, m2), m3);
    float ss = 0.f;
#pragma unroll
    for (int ii = 0; ii < 7; ++ii) ss += exp2f((x[ii] - mm) * LOG2E);
    float s1 = __shfl(ss, j, 64);
    float s2 = __shfl(ss, j + 21, 64);
    float s3 = __shfl(ss, j + 42, 64);
    float anew = e + mm + LN2 * log2f(s1 + s2 + s3);
    a = mk ? anew : a;
  }

  // ---- logZ = logsumexp_j(alpha[j] + end[j])
  float y  = (lane < T) ? a + end_t[lane] : -3e38f;
  float ym = y;
#pragma unroll
  for (int m = 32; m; m >>= 1) ym = fmaxf(ym, __shfl_xor(ym, m, 64));
  float z = (lane < T) ? exp2f((y - ym) * LOG2E) : 0.f;
#pragma unroll
  for (int m = 32; m; m >>= 1) z += __shfl_xor(z, m, 64);
  float logZ = ym + LN2 * log2f(z);

  if (lane == 0) part[b] = logZ - num;
}

// ---------------------------------------------------------------------------
// Kernel 3: loss = sum_b part[b]
// ---------------------------------------------------------------------------
__global__ void k_loss(const float* __restrict__ part, float* __restrict__ out_loss) {
  int lane = threadIdx.x;
  float v = part[lane];                  // B == 64 exactly
#pragma unroll
  for (int m = 32; m; m >>= 1) v += __shfl_xor(v, m, 64);
  if (lane == 0) out_loss[0] = v;
}

// ---------------------------------------------------------------------------
extern "C" void kernel_launch(void* const* d_in, const int* in_sizes, int n_in,
                              void* d_out, int out_size, void* d_ws, size_t ws_size,
                              hipStream_t stream) {
  const float* seq  = (const float*)d_in[0];
  const int*   ids  = (const int*)  d_in[1];
  const float* wts  = (const float*)d_in[2];
  const int*   lbl  = (const int*)  d_in[3];
  const int*   msk  = (const int*)  d_in[4];
  const float* emb  = (const float*)d_in[5];
  const float* W    = (const float*)d_in[6];
  const float* bias = (const float*)d_in[7];
  const float* st   = (const float*)d_in[8];
  const float* en   = (const float*)d_in[9];
  const float* tr   = (const float*)d_in[10];

  float* out  = (float*)d_out;           // [NT*T logits][1 loss]
  float* Wp   = (float*)d_ws;            // 21*1024 floats
  float* part = Wp + T * HP;             // 64 floats

  k_wprep <<<(T * HP + 255) / 256, 256, 0, stream>>>(W, Wp);
  k_logits<<<NT / (4 * TPW), 256, 0, stream>>>(seq, ids, wts, emb, Wp, bias, out);
  k_crf   <<<B, 64, 0, stream>>>(out, lbl, msk, st, en, tr, part);
  k_loss  <<<1, 64, 0, stream>>>(part, out + (long)NT * T);
}